// Round 6
// baseline (297.357 us; speedup 1.0000x reference)
//
#include <hip/hip_runtime.h>
#include <hip/hip_bf16.h>
#include <cstdint>
#include <cstddef>

#define BS   4
#define NN   2048
#define NH   2
#define FIN  768
#define FOUT 768
#define NEG_SLOPE 0.2f

typedef __attribute__((ext_vector_type(8))) short short8;
typedef __attribute__((ext_vector_type(4))) float float4v;

static __device__ __forceinline__ float bits2f(unsigned short u) {
    union { unsigned int i; float f; } v; v.i = ((unsigned int)u) << 16; return v.f;
}
// RNE fp32 -> bf16 bits
static __device__ __forceinline__ unsigned short f2bits(float f) {
    union { float f; unsigned int i; } v; v.f = f;
    unsigned int x = v.i;
    unsigned int r = x + 0x7fffu + ((x >> 16) & 1u);
    return (unsigned short)(r >> 16);
}
// fast tanh via hardware exp; rel err ~1e-6
static __device__ __forceinline__ float fast_tanh(float x) {
    float xc = fminf(fmaxf(x, -20.f), 20.f);
    float e = __expf(2.f * xc);
    return (e - 1.f) / (e + 1.f);
}
// async global->LDS, 16B per lane; lds base wave-uniform, lane lands at +lane*16
static __device__ __forceinline__ void async_copy16(void* lds, const void* g) {
    __builtin_amdgcn_global_load_lds(
        (const __attribute__((address_space(1))) unsigned int*)g,
        (__attribute__((address_space(3))) unsigned int*)lds, 16, 0, 0);
}

// Per-block dtype detection (wave ballot; uniform result)
static __device__ __forceinline__ bool detect_isf32(const unsigned short* h_raw) {
    unsigned short u = h_raw[threadIdx.x & 63];
    int e = (u >> 7) & 0xFF;
    unsigned long long m = __ballot(e >= 118 && e <= 134);
    return __popcll(m) < 48;
}
static __device__ __forceinline__ bool detect_adj8(const unsigned char* adj_raw) {
    int l = threadIdx.x & 63;
    unsigned char v = (unsigned char)(adj_raw[l * 4 + 1] | adj_raw[l * 4 + 2] |
                                      adj_raw[l * 4 + 3]);
    unsigned long long m = __ballot(v != 0);
    return __popcll(m) > 8;
}

// ---------------------------------------------------------------------------
// K_prep (single launch): [0,3072) h->bf16; [3072,4224) w transpose;
// [4224,4352) zero attn acc; [4352] a_src/a_dst/bias -> f32
// ---------------------------------------------------------------------------
#define NB_H   3072   // BS*NN*FIN / 2048
#define NB_W   1152   // (FIN/32)*(FOUT/32)*NH
#define NB_Z   128    // 2*BS*NH*NN / 256
__global__ __launch_bounds__(256) void k_prep(
    const void* __restrict__ hr, unsigned short* __restrict__ h_bf,
    const void* __restrict__ wr, unsigned short* __restrict__ wt_b,
    const void* __restrict__ as_raw, const void* __restrict__ ad_raw,
    const void* __restrict__ b_raw,
    float* __restrict__ asf, float* __restrict__ adf, float* __restrict__ bff,
    float* __restrict__ attn_acc)
{
    __shared__ float tile[32][33];
    int bi = blockIdx.x;
    int t = threadIdx.x;
    if (bi < NB_H) {
        bool isf = detect_isf32((const unsigned short*)hr);
        int base = (bi * 256 + t) * 8;
        if (isf) {
            float4 f0 = *((const float4*)((const float*)hr + base));
            float4 f1 = *((const float4*)((const float*)hr + base + 4));
            unsigned short v[8] = { f2bits(f0.x), f2bits(f0.y), f2bits(f0.z), f2bits(f0.w),
                                    f2bits(f1.x), f2bits(f1.y), f2bits(f1.z), f2bits(f1.w) };
            *(uint4*)(h_bf + base) = *(const uint4*)v;
        } else {
            *(uint4*)(h_bf + base) = *(const uint4*)((const unsigned short*)hr + base);
        }
        return;
    }
    if (bi < NB_H + NB_W) {
        bool isf = detect_isf32((const unsigned short*)hr);
        int wb = bi - NB_H;
        int h  = wb / 576;           // (FIN/32)*(FOUT/32) = 576
        int rem = wb % 576;
        int f0 = (rem % 24) * 32;
        int o0 = (rem / 24) * 32;
        int tx = t & 31, ty = t >> 5;     // 32 x 8
        #pragma unroll
        for (int r = 0; r < 4; ++r) {
            int fl = ty * 4 + r;
            size_t idx = (size_t)h * FIN * FOUT + (size_t)(f0 + fl) * FOUT + (o0 + tx);
            tile[fl][tx] = isf ? ((const float*)wr)[idx]
                               : bits2f(((const unsigned short*)wr)[idx]);
        }
        __syncthreads();
        #pragma unroll
        for (int r = 0; r < 4; ++r) {
            int ol = ty * 4 + r;
            size_t oidx = (size_t)h * FOUT * FIN + (size_t)(o0 + ol) * FIN + (f0 + tx);
            wt_b[oidx] = f2bits(tile[tx][ol]);
        }
        return;
    }
    if (bi < NB_H + NB_W + NB_Z) {
        attn_acc[(bi - NB_H - NB_W) * 256 + t] = 0.f;
        return;
    }
    bool isf = detect_isf32((const unsigned short*)hr);
    for (int i = t; i < NH * FOUT; i += 256) {
        asf[i] = isf ? ((const float*)as_raw)[i] : bits2f(((const unsigned short*)as_raw)[i]);
        adf[i] = isf ? ((const float*)ad_raw)[i] : bits2f(((const unsigned short*)ad_raw)[i]);
    }
    for (int i = t; i < FOUT; i += 256)
        bff[i] = isf ? ((const float*)b_raw)[i] : bits2f(((const unsigned short*)b_raw)[i]);
}

// ---------------------------------------------------------------------------
// GEMM geometry: 128x128 tile, BK=64 (32 MFMA per barrier), 4 waves, 4x4
// 16x16x32 MFMA per wave. LDS unpadded [row][64]; swizzle: global chunk
// gc = ((cc&3)^((rr>>1)&3)) | ((((cc>>2)^rr)&1)<<2) stored at lane slot cc;
// read slot = (kk^(lm&1))*4 + (quad^((lm>>1)&3)) -> 2 lanes/bank (free).
// ---------------------------------------------------------------------------
#define BM 128
#define BN 128
#define BK 64

// K1: hpT[bh][o][n] = sum_f h[b][n][f]*w[h][f][o]; fused attn_src/dst epilogue
__global__ __launch_bounds__(256) void k_gemm_hw(
    const unsigned short* __restrict__ hh,
    const unsigned short* __restrict__ wh,
    unsigned short* __restrict__ hpT,
    const float* __restrict__ asf, const float* __restrict__ adf,
    float* __restrict__ attn_src, float* __restrict__ attn_dst)
{
    int ib = blockIdx.z;                      // bh
    int b  = ib / NH, hd = ib % NH;
    int i0 = blockIdx.x * BM;
    int o0 = blockIdx.y * BN;
    const unsigned short* A  = hh + (size_t)b  * NN * FIN;
    const unsigned short* Bt = wh + (size_t)hd * FOUT * FIN;
    unsigned short*       C  = hpT + (size_t)ib * FOUT * NN;

    __shared__ __align__(16) unsigned short As[BM * BK];
    __shared__ __align__(16) unsigned short Bs[BN * BK];

    int t = threadIdx.x;
    int lane = t & 63, wave = t >> 6;
    int wm = (wave & 1) * 64, wn = (wave >> 1) * 64;
    int lm = lane & 15, quad = lane >> 4;
    int rr = lane >> 3;                       // staging row 0..7
    int cc = lane & 7;                        // staging slot 0..7
    int gc = ((cc & 3) ^ ((rr >> 1) & 3)) | ((((cc >> 2) ^ rr) & 1) << 2);
    int sA = (lm >> 1) & 3;
    int sP = lm & 1;

    float4v acc[4][4] = {};

    for (int k0 = 0; k0 < FIN; k0 += BK) {
        __syncthreads();
        #pragma unroll
        for (int p = 0; p < 4; ++p) {
            int r0 = wave * 32 + p * 8;
            async_copy16(&As[r0 * BK], A  + (size_t)(i0 + r0 + rr) * FIN + k0 + gc * 8);
            async_copy16(&Bs[r0 * BK], Bt + (size_t)(o0 + r0 + rr) * FIN + k0 + gc * 8);
        }
        __syncthreads();
        #pragma unroll
        for (int kk = 0; kk < 2; ++kk) {
            int so = ((kk ^ sP) << 2);
            short8 fa[4], fb[4];
            #pragma unroll
            for (int mt = 0; mt < 4; ++mt)
                fa[mt] = *(const short8*)&As[(wm + mt * 16 + lm) * BK + (so + (quad ^ sA)) * 8];
            #pragma unroll
            for (int nt = 0; nt < 4; ++nt)
                fb[nt] = *(const short8*)&Bs[(wn + nt * 16 + lm) * BK + (so + (quad ^ sA)) * 8];
            #pragma unroll
            for (int mt = 0; mt < 4; ++mt)
                #pragma unroll
                for (int nt = 0; nt < 4; ++nt)
                    acc[mt][nt] = __builtin_amdgcn_mfma_f32_16x16x32_bf16(
                        fa[mt], fb[nt], acc[mt][nt], 0, 0, 0);
        }
    }

    // epilogue: store hpT + fused tanh-dot partials for attn_src/dst
    float asv[4], adv[4];
    #pragma unroll
    for (int nt = 0; nt < 4; ++nt) {
        int o = o0 + wn + nt * 16 + lm;
        asv[nt] = asf[hd * FOUT + o];
        adv[nt] = adf[hd * FOUT + o];
    }
    #pragma unroll
    for (int mt = 0; mt < 4; ++mt) {
        float ps[4] = {0.f, 0.f, 0.f, 0.f};
        float pd[4] = {0.f, 0.f, 0.f, 0.f};
        #pragma unroll
        for (int nt = 0; nt < 4; ++nt) {
            int node = i0 + wm + mt * 16 + quad * 4;
            int o    = o0 + wn + nt * 16 + lm;
            ushort4 v;
            v.x = f2bits(acc[mt][nt][0]);
            v.y = f2bits(acc[mt][nt][1]);
            v.z = f2bits(acc[mt][nt][2]);
            v.w = f2bits(acc[mt][nt][3]);
            *(ushort4*)&C[(size_t)o * NN + node] = v;
            #pragma unroll
            for (int r = 0; r < 4; ++r) {
                float tv = fast_tanh(acc[mt][nt][r]);
                ps[r] += tv * asv[nt];
                pd[r] += tv * adv[nt];
            }
        }
        #pragma unroll
        for (int r = 0; r < 4; ++r) {
            float s = ps[r], d = pd[r];
            #pragma unroll
            for (int off = 1; off <= 8; off <<= 1) {
                s += __shfl_xor(s, off);
                d += __shfl_xor(d, off);
            }
            if (lm == 0) {
                int node = i0 + wm + mt * 16 + quad * 4 + r;
                atomicAdd(&attn_src[ib * NN + node], s);
                atomicAdd(&attn_dst[ib * NN + node], d);
            }
        }
    }
}

// ---------------------------------------------------------------------------
// K3: per (b,i): read adj row once, softmax for both heads, write P rows
// ---------------------------------------------------------------------------
__global__ __launch_bounds__(256) void k_softmax_p(
    const float* __restrict__ attn_src, const float* __restrict__ attn_dst,
    const void* __restrict__ adj_raw,
    unsigned short* __restrict__ P)
{
    int blk = blockIdx.x;                     // b*NN + i
    int i = blk & (NN - 1);
    int b = blk >> 11;
    bool is8 = detect_adj8((const unsigned char*)adj_raw);
    int t = threadIdx.x;
    int lane = t & 63, wave = t >> 6;
    int j0 = t * 8;

    bool keep[8];
    if (is8) {
        const unsigned char* arow = (const unsigned char*)adj_raw + ((size_t)b * NN + i) * NN;
        uint2 v = *(const uint2*)(arow + j0);
        #pragma unroll
        for (int r = 0; r < 8; ++r) {
            unsigned int w = (r < 4) ? v.x : v.y;
            keep[r] = ((w >> ((r & 3) * 8)) & 0xFFu) != 0;
        }
    } else {
        const int* arow = (const int*)adj_raw + ((size_t)b * NN + i) * NN;
        int4 v0 = *(const int4*)(arow + j0);
        int4 v1 = *(const int4*)(arow + j0 + 4);
        keep[0] = v0.x != 0; keep[1] = v0.y != 0; keep[2] = v0.z != 0; keep[3] = v0.w != 0;
        keep[4] = v1.x != 0; keep[5] = v1.y != 0; keep[6] = v1.z != 0; keep[7] = v1.w != 0;
    }
    #pragma unroll
    for (int r = 0; r < 8; ++r) keep[r] = keep[r] || (j0 + r == i);

    __shared__ float redm[4], reds[4];
    for (int hh = 0; hh < NH; ++hh) {
        int bh = b * NH + hh;
        float src = attn_src[bh * NN + i];
        const float* drow = attn_dst + (size_t)bh * NN;
        float4 d0 = *(const float4*)(drow + j0);
        float4 d1 = *(const float4*)(drow + j0 + 4);
        float dj[8] = { d0.x, d0.y, d0.z, d0.w, d1.x, d1.y, d1.z, d1.w };

        float s[8];
        float lmax = -1e30f;
        #pragma unroll
        for (int r = 0; r < 8; ++r) {
            float sc = src + dj[r];
            sc = sc >= 0.f ? sc : NEG_SLOPE * sc;
            s[r] = keep[r] ? sc : -1e30f;
            lmax = fmaxf(lmax, s[r]);
        }
        __syncthreads();
        #pragma unroll
        for (int off = 32; off > 0; off >>= 1)
            lmax = fmaxf(lmax, __shfl_xor(lmax, off));
        if (lane == 0) redm[wave] = lmax;
        __syncthreads();
        float m = fmaxf(fmaxf(redm[0], redm[1]), fmaxf(redm[2], redm[3]));

        float p[8];
        float lsum = 0.f;
        #pragma unroll
        for (int r = 0; r < 8; ++r) {
            p[r] = __expf(s[r] - m);
            lsum += p[r];
        }
        #pragma unroll
        for (int off = 32; off > 0; off >>= 1)
            lsum += __shfl_xor(lsum, off);
        if (lane == 0) reds[wave] = lsum;
        __syncthreads();
        float inv = 1.0f / (reds[0] + reds[1] + reds[2] + reds[3]);

        uint4 pw;
        pw.x = ((unsigned int)f2bits(p[1] * inv) << 16) | f2bits(p[0] * inv);
        pw.y = ((unsigned int)f2bits(p[3] * inv) << 16) | f2bits(p[2] * inv);
        pw.z = ((unsigned int)f2bits(p[5] * inv) << 16) | f2bits(p[4] * inv);
        pw.w = ((unsigned int)f2bits(p[7] * inv) << 16) | f2bits(p[6] * inv);
        *(uint4*)&P[((size_t)bh * NN + i) * NN + j0] = pw;
    }
}

// ---------------------------------------------------------------------------
// K4: out[bh][i][o] = sum_j P[i][j]*hpT[o][j] + bias[o]
// Grid: x = o-tile (fastest) so consecutive blocks share the P i-tile in L2.
// ---------------------------------------------------------------------------
__global__ __launch_bounds__(256) void k_gemm_out(
    const unsigned short* __restrict__ P,
    const unsigned short* __restrict__ hpT,
    const float* __restrict__ bf,
    void* __restrict__ outp, const unsigned short* __restrict__ h_raw)
{
    bool isf = detect_isf32(h_raw);
    int ib = blockIdx.z;
    int o0 = blockIdx.x * BN;
    int i0 = blockIdx.y * BM;
    const unsigned short* A  = P   + (size_t)ib * NN * NN;
    const unsigned short* Bt = hpT + (size_t)ib * FOUT * NN;

    __shared__ __align__(16) unsigned short As[BM * BK];
    __shared__ __align__(16) unsigned short Bs[BN * BK];

    int t = threadIdx.x;
    int lane = t & 63, wave = t >> 6;
    int wm = (wave & 1) * 64, wn = (wave >> 1) * 64;
    int lm = lane & 15, quad = lane >> 4;
    int rr = lane >> 3;
    int cc = lane & 7;
    int gc = ((cc & 3) ^ ((rr >> 1) & 3)) | ((((cc >> 2) ^ rr) & 1) << 2);
    int sA = (lm >> 1) & 3;
    int sP = lm & 1;

    float4v acc[4][4] = {};

    for (int k0 = 0; k0 < NN; k0 += BK) {
        __syncthreads();
        #pragma unroll
        for (int p = 0; p < 4; ++p) {
            int r0 = wave * 32 + p * 8;
            async_copy16(&As[r0 * BK], A  + (size_t)(i0 + r0 + rr) * NN + k0 + gc * 8);
            async_copy16(&Bs[r0 * BK], Bt + (size_t)(o0 + r0 + rr) * NN + k0 + gc * 8);
        }
        __syncthreads();
        #pragma unroll
        for (int kk = 0; kk < 2; ++kk) {
            int so = ((kk ^ sP) << 2);
            short8 fa[4], fb[4];
            #pragma unroll
            for (int mt = 0; mt < 4; ++mt)
                fa[mt] = *(const short8*)&As[(wm + mt * 16 + lm) * BK + (so + (quad ^ sA)) * 8];
            #pragma unroll
            for (int nt = 0; nt < 4; ++nt)
                fb[nt] = *(const short8*)&Bs[(wn + nt * 16 + lm) * BK + (so + (quad ^ sA)) * 8];
            #pragma unroll
            for (int mt = 0; mt < 4; ++mt)
                #pragma unroll
                for (int nt = 0; nt < 4; ++nt)
                    acc[mt][nt] = __builtin_amdgcn_mfma_f32_16x16x32_bf16(
                        fa[mt], fb[nt], acc[mt][nt], 0, 0, 0);
        }
    }

    if (isf) {
        float* C = (float*)outp + (size_t)ib * NN * FOUT;
        #pragma unroll
        for (int nt = 0; nt < 4; ++nt) {
            int o = o0 + wn + nt * 16 + lm;
            float bv = bf[o];
            #pragma unroll
            for (int mt = 0; mt < 4; ++mt) {
                int i = i0 + wm + mt * 16 + quad * 4;
                #pragma unroll
                for (int r = 0; r < 4; ++r)
                    C[(size_t)(i + r) * FOUT + o] = acc[mt][nt][r] + bv;
            }
        }
    } else {
        unsigned short* C = (unsigned short*)outp + (size_t)ib * NN * FOUT;
        #pragma unroll
        for (int nt = 0; nt < 4; ++nt) {
            int o = o0 + wn + nt * 16 + lm;
            float bv = bf[o];
            #pragma unroll
            for (int mt = 0; mt < 4; ++mt) {
                int i = i0 + wm + mt * 16 + quad * 4;
                #pragma unroll
                for (int r = 0; r < 4; ++r)
                    C[(size_t)(i + r) * FOUT + o] = f2bits(acc[mt][nt][r] + bv);
            }
        }
    }
}

// ---------------------------------------------------------------------------
extern "C" void kernel_launch(void* const* d_in, const int* in_sizes, int n_in,
                              void* d_out, int out_size, void* d_ws, size_t ws_size,
                              hipStream_t stream)
{
    const void* h_raw   = d_in[0];
    const void* adj_raw = d_in[1];
    const void* w_raw   = d_in[2];
    const void* as_raw  = d_in[3];
    const void* ad_raw  = d_in[4];
    const void* b_raw   = d_in[5];

    char* ws = (char*)d_ws;
    size_t off = 0;
    unsigned short* hpT = (unsigned short*)(ws + off); off += (size_t)BS * NH * FOUT * NN * 2;
    float* asr = (float*)(ws + off);            off += (size_t)BS * NH * NN * 4;
    float* ads = (float*)(ws + off);            off += (size_t)BS * NH * NN * 4;
    // union: {h_bf16, wt_bf16} live only until k_gemm_hw; P overlays after.
    size_t uoff = off;
    unsigned short* P    = (unsigned short*)(ws + uoff);
    unsigned short* h_bf = (unsigned short*)(ws + uoff); uoff += (size_t)BS * NN * FIN * 2;
    unsigned short* wt_b = (unsigned short*)(ws + uoff); uoff += (size_t)NH * FOUT * FIN * 2;
    off += (size_t)BS * NH * NN * NN * 2;       // P dominates the union
    float* asf = (float*)(ws + off);            off += (size_t)NH * FOUT * 4;
    float* adf = (float*)(ws + off);            off += (size_t)NH * FOUT * 4;
    float* bff = (float*)(ws + off);            off += 4096;

    k_prep<<<NB_H + NB_W + NB_Z + 1, 256, 0, stream>>>(
        h_raw, h_bf, w_raw, wt_b, as_raw, ad_raw, b_raw, asf, adf, bff, asr);
    k_gemm_hw<<<dim3(NN / BM, FOUT / BN, BS * NH), 256, 0, stream>>>(
        h_bf, wt_b, hpT, asf, adf, asr, ads);
    k_softmax_p<<<dim3(BS * NN), 256, 0, stream>>>(asr, ads, adj_raw, P);
    k_gemm_out<<<dim3(FOUT / BN, NN / BM, BS * NH), 256, 0, stream>>>(
        P, hpT, bff, d_out, (const unsigned short*)h_raw);
}

// Round 7
// 280.818 us; speedup vs baseline: 1.0589x; 1.0589x over previous
//
#include <hip/hip_runtime.h>
#include <hip/hip_bf16.h>
#include <cstdint>
#include <cstddef>

#define BS   4
#define NN   2048
#define NH   2
#define FIN  768
#define FOUT 768
#define NEG_SLOPE 0.2f

typedef __attribute__((ext_vector_type(8))) short short8;
typedef __attribute__((ext_vector_type(4))) float float4v;

static __device__ __forceinline__ float bits2f(unsigned short u) {
    union { unsigned int i; float f; } v; v.i = ((unsigned int)u) << 16; return v.f;
}
// RNE fp32 -> bf16 bits
static __device__ __forceinline__ unsigned short f2bits(float f) {
    union { float f; unsigned int i; } v; v.f = f;
    unsigned int x = v.i;
    unsigned int r = x + 0x7fffu + ((x >> 16) & 1u);
    return (unsigned short)(r >> 16);
}
// fast tanh via hardware exp; rel err ~1e-6
static __device__ __forceinline__ float fast_tanh(float x) {
    float xc = fminf(fmaxf(x, -20.f), 20.f);
    float e = __expf(2.f * xc);
    return (e - 1.f) / (e + 1.f);
}
// async global->LDS, 16B per lane; lds base wave-uniform, lane lands at +lane*16
static __device__ __forceinline__ void async_copy16(void* lds, const void* g) {
    __builtin_amdgcn_global_load_lds(
        (const __attribute__((address_space(1))) unsigned int*)g,
        (__attribute__((address_space(3))) unsigned int*)lds, 16, 0, 0);
}

// Per-block dtype detection (wave ballot; uniform result)
static __device__ __forceinline__ bool detect_isf32(const unsigned short* h_raw) {
    unsigned short u = h_raw[threadIdx.x & 63];
    int e = (u >> 7) & 0xFF;
    unsigned long long m = __ballot(e >= 118 && e <= 134);
    return __popcll(m) < 48;
}
static __device__ __forceinline__ bool detect_adj8(const unsigned char* adj_raw) {
    int l = threadIdx.x & 63;
    unsigned char v = (unsigned char)(adj_raw[l * 4 + 1] | adj_raw[l * 4 + 2] |
                                      adj_raw[l * 4 + 3]);
    unsigned long long m = __ballot(v != 0);
    return __popcll(m) > 8;
}

// ---------------------------------------------------------------------------
// K_prep (single launch): [0,3072) h->bf16; [3072,4224) w transpose;
// [4224,4352) zero attn acc; [4352] a_src/a_dst/bias -> f32
// ---------------------------------------------------------------------------
#define NB_H   3072   // BS*NN*FIN / 2048
#define NB_W   1152   // (FIN/32)*(FOUT/32)*NH
#define NB_Z   128    // 2*BS*NH*NN / 256
__global__ __launch_bounds__(256) void k_prep(
    const void* __restrict__ hr, unsigned short* __restrict__ h_bf,
    const void* __restrict__ wr, unsigned short* __restrict__ wt_b,
    const void* __restrict__ as_raw, const void* __restrict__ ad_raw,
    const void* __restrict__ b_raw,
    float* __restrict__ asf, float* __restrict__ adf, float* __restrict__ bff,
    float* __restrict__ attn_acc)
{
    __shared__ float tile[32][33];
    int bi = blockIdx.x;
    int t = threadIdx.x;
    if (bi < NB_H) {
        bool isf = detect_isf32((const unsigned short*)hr);
        int base = (bi * 256 + t) * 8;
        if (isf) {
            float4 f0 = *((const float4*)((const float*)hr + base));
            float4 f1 = *((const float4*)((const float*)hr + base + 4));
            unsigned short v[8] = { f2bits(f0.x), f2bits(f0.y), f2bits(f0.z), f2bits(f0.w),
                                    f2bits(f1.x), f2bits(f1.y), f2bits(f1.z), f2bits(f1.w) };
            *(uint4*)(h_bf + base) = *(const uint4*)v;
        } else {
            *(uint4*)(h_bf + base) = *(const uint4*)((const unsigned short*)hr + base);
        }
        return;
    }
    if (bi < NB_H + NB_W) {
        bool isf = detect_isf32((const unsigned short*)hr);
        int wb = bi - NB_H;
        int h  = wb / 576;           // (FIN/32)*(FOUT/32) = 576
        int rem = wb % 576;
        int f0 = (rem % 24) * 32;
        int o0 = (rem / 24) * 32;
        int tx = t & 31, ty = t >> 5;     // 32 x 8
        #pragma unroll
        for (int r = 0; r < 4; ++r) {
            int fl = ty * 4 + r;
            size_t idx = (size_t)h * FIN * FOUT + (size_t)(f0 + fl) * FOUT + (o0 + tx);
            tile[fl][tx] = isf ? ((const float*)wr)[idx]
                               : bits2f(((const unsigned short*)wr)[idx]);
        }
        __syncthreads();
        #pragma unroll
        for (int r = 0; r < 4; ++r) {
            int ol = ty * 4 + r;
            size_t oidx = (size_t)h * FOUT * FIN + (size_t)(o0 + ol) * FIN + (f0 + tx);
            wt_b[oidx] = f2bits(tile[tx][ol]);
        }
        return;
    }
    if (bi < NB_H + NB_W + NB_Z) {
        attn_acc[(bi - NB_H - NB_W) * 256 + t] = 0.f;
        return;
    }
    bool isf = detect_isf32((const unsigned short*)hr);
    for (int i = t; i < NH * FOUT; i += 256) {
        asf[i] = isf ? ((const float*)as_raw)[i] : bits2f(((const unsigned short*)as_raw)[i]);
        adf[i] = isf ? ((const float*)ad_raw)[i] : bits2f(((const unsigned short*)ad_raw)[i]);
    }
    for (int i = t; i < FOUT; i += 256)
        bff[i] = isf ? ((const float*)b_raw)[i] : bits2f(((const unsigned short*)b_raw)[i]);
}

// ---------------------------------------------------------------------------
// GEMM geometry: 128x128 tile, BK=64 (32 MFMA per barrier pair), 4 waves,
// 4x4 16x16x32 MFMA per wave. LDS unpadded [row][64] (128B row = 32 banks).
// XOR swizzle: slot cc of row r holds global chunk (cc ^ (r&7)); rows are
// staged in groups of 8 so (r&7)=rr. Read slot = ((kk*4+quad) ^ (lm&7)) ->
// every slot-group hit by exactly 8 lanes = conflict-free minimum.
// ---------------------------------------------------------------------------
#define BM 128
#define BN 128
#define BK 64

// K1: hpT[bh][o][n] = sum_f h[b][n][f]*w[h][f][o]; fused attn_src/dst epilogue
__global__ __launch_bounds__(256) void k_gemm_hw(
    const unsigned short* __restrict__ hh,
    const unsigned short* __restrict__ wh,
    unsigned short* __restrict__ hpT,
    const float* __restrict__ asf, const float* __restrict__ adf,
    float* __restrict__ attn_src, float* __restrict__ attn_dst)
{
    int ib = blockIdx.z;                      // bh
    int b  = ib / NH, hd = ib % NH;
    int i0 = blockIdx.x * BM;
    int o0 = blockIdx.y * BN;
    const unsigned short* A  = hh + (size_t)b  * NN * FIN;
    const unsigned short* Bt = wh + (size_t)hd * FOUT * FIN;
    unsigned short*       C  = hpT + (size_t)ib * FOUT * NN;

    __shared__ __align__(16) unsigned short As[BM * BK];
    __shared__ __align__(16) unsigned short Bs[BN * BK];

    int t = threadIdx.x;
    int lane = t & 63, wave = t >> 6;
    int wm = (wave & 1) * 64, wn = (wave >> 1) * 64;
    int lm = lane & 15, quad = lane >> 4;
    int rr = lane >> 3;                       // staging row 0..7
    int cc = lane & 7;                        // staging slot 0..7
    int gc = cc ^ rr;                         // global chunk at this slot
    int e  = lm & 7;                          // read-side row parity

    float4v acc[4][4] = {};

    for (int k0 = 0; k0 < FIN; k0 += BK) {
        __syncthreads();
        #pragma unroll
        for (int p = 0; p < 4; ++p) {
            int r0 = wave * 32 + p * 8;
            async_copy16(&As[r0 * BK], A  + (size_t)(i0 + r0 + rr) * FIN + k0 + gc * 8);
            async_copy16(&Bs[r0 * BK], Bt + (size_t)(o0 + r0 + rr) * FIN + k0 + gc * 8);
        }
        __syncthreads();
        #pragma unroll
        for (int kk = 0; kk < 2; ++kk) {
            int slot = ((kk << 2) | quad) ^ e;
            short8 fa[4], fb[4];
            #pragma unroll
            for (int mt = 0; mt < 4; ++mt)
                fa[mt] = *(const short8*)&As[(wm + mt * 16 + lm) * BK + slot * 8];
            #pragma unroll
            for (int nt = 0; nt < 4; ++nt)
                fb[nt] = *(const short8*)&Bs[(wn + nt * 16 + lm) * BK + slot * 8];
            #pragma unroll
            for (int mt = 0; mt < 4; ++mt)
                #pragma unroll
                for (int nt = 0; nt < 4; ++nt)
                    acc[mt][nt] = __builtin_amdgcn_mfma_f32_16x16x32_bf16(
                        fa[mt], fb[nt], acc[mt][nt], 0, 0, 0);
        }
    }

    // epilogue: store hpT + fused tanh-dot partials for attn_src/dst
    float asv[4], adv[4];
    #pragma unroll
    for (int nt = 0; nt < 4; ++nt) {
        int o = o0 + wn + nt * 16 + lm;
        asv[nt] = asf[hd * FOUT + o];
        adv[nt] = adf[hd * FOUT + o];
    }
    #pragma unroll
    for (int mt = 0; mt < 4; ++mt) {
        float ps[4] = {0.f, 0.f, 0.f, 0.f};
        float pd[4] = {0.f, 0.f, 0.f, 0.f};
        #pragma unroll
        for (int nt = 0; nt < 4; ++nt) {
            int node = i0 + wm + mt * 16 + quad * 4;
            int o    = o0 + wn + nt * 16 + lm;
            ushort4 v;
            v.x = f2bits(acc[mt][nt][0]);
            v.y = f2bits(acc[mt][nt][1]);
            v.z = f2bits(acc[mt][nt][2]);
            v.w = f2bits(acc[mt][nt][3]);
            *(ushort4*)&C[(size_t)o * NN + node] = v;
            #pragma unroll
            for (int r = 0; r < 4; ++r) {
                float tv = fast_tanh(acc[mt][nt][r]);
                ps[r] += tv * asv[nt];
                pd[r] += tv * adv[nt];
            }
        }
        #pragma unroll
        for (int r = 0; r < 4; ++r) {
            float s = ps[r], d = pd[r];
            #pragma unroll
            for (int off = 1; off <= 8; off <<= 1) {
                s += __shfl_xor(s, off);
                d += __shfl_xor(d, off);
            }
            if (lm == 0) {
                int node = i0 + wm + mt * 16 + quad * 4 + r;
                atomicAdd(&attn_src[ib * NN + node], s);
                atomicAdd(&attn_dst[ib * NN + node], d);
            }
        }
    }
}

// ---------------------------------------------------------------------------
// K3: per (b,i): read adj row once, softmax for both heads, write P rows
// ---------------------------------------------------------------------------
__global__ __launch_bounds__(256) void k_softmax_p(
    const float* __restrict__ attn_src, const float* __restrict__ attn_dst,
    const void* __restrict__ adj_raw,
    unsigned short* __restrict__ P)
{
    int blk = blockIdx.x;                     // b*NN + i
    int i = blk & (NN - 1);
    int b = blk >> 11;
    bool is8 = detect_adj8((const unsigned char*)adj_raw);
    int t = threadIdx.x;
    int lane = t & 63, wave = t >> 6;
    int j0 = t * 8;

    bool keep[8];
    if (is8) {
        const unsigned char* arow = (const unsigned char*)adj_raw + ((size_t)b * NN + i) * NN;
        uint2 v = *(const uint2*)(arow + j0);
        #pragma unroll
        for (int r = 0; r < 8; ++r) {
            unsigned int w = (r < 4) ? v.x : v.y;
            keep[r] = ((w >> ((r & 3) * 8)) & 0xFFu) != 0;
        }
    } else {
        const int* arow = (const int*)adj_raw + ((size_t)b * NN + i) * NN;
        int4 v0 = *(const int4*)(arow + j0);
        int4 v1 = *(const int4*)(arow + j0 + 4);
        keep[0] = v0.x != 0; keep[1] = v0.y != 0; keep[2] = v0.z != 0; keep[3] = v0.w != 0;
        keep[4] = v1.x != 0; keep[5] = v1.y != 0; keep[6] = v1.z != 0; keep[7] = v1.w != 0;
    }
    #pragma unroll
    for (int r = 0; r < 8; ++r) keep[r] = keep[r] || (j0 + r == i);

    __shared__ float redm[4], reds[4];
    for (int hh = 0; hh < NH; ++hh) {
        int bh = b * NH + hh;
        float src = attn_src[bh * NN + i];
        const float* drow = attn_dst + (size_t)bh * NN;
        float4 d0 = *(const float4*)(drow + j0);
        float4 d1 = *(const float4*)(drow + j0 + 4);
        float dj[8] = { d0.x, d0.y, d0.z, d0.w, d1.x, d1.y, d1.z, d1.w };

        float s[8];
        float lmax = -1e30f;
        #pragma unroll
        for (int r = 0; r < 8; ++r) {
            float sc = src + dj[r];
            sc = sc >= 0.f ? sc : NEG_SLOPE * sc;
            s[r] = keep[r] ? sc : -1e30f;
            lmax = fmaxf(lmax, s[r]);
        }
        __syncthreads();
        #pragma unroll
        for (int off = 32; off > 0; off >>= 1)
            lmax = fmaxf(lmax, __shfl_xor(lmax, off));
        if (lane == 0) redm[wave] = lmax;
        __syncthreads();
        float m = fmaxf(fmaxf(redm[0], redm[1]), fmaxf(redm[2], redm[3]));

        float p[8];
        float lsum = 0.f;
        #pragma unroll
        for (int r = 0; r < 8; ++r) {
            p[r] = __expf(s[r] - m);
            lsum += p[r];
        }
        #pragma unroll
        for (int off = 32; off > 0; off >>= 1)
            lsum += __shfl_xor(lsum, off);
        if (lane == 0) reds[wave] = lsum;
        __syncthreads();
        float inv = 1.0f / (reds[0] + reds[1] + reds[2] + reds[3]);

        uint4 pw;
        pw.x = ((unsigned int)f2bits(p[1] * inv) << 16) | f2bits(p[0] * inv);
        pw.y = ((unsigned int)f2bits(p[3] * inv) << 16) | f2bits(p[2] * inv);
        pw.z = ((unsigned int)f2bits(p[5] * inv) << 16) | f2bits(p[4] * inv);
        pw.w = ((unsigned int)f2bits(p[7] * inv) << 16) | f2bits(p[6] * inv);
        *(uint4*)&P[((size_t)bh * NN + i) * NN + j0] = pw;
    }
}

// ---------------------------------------------------------------------------
// K4: out[bh][i][o] = sum_j P[i][j]*hpT[o][j] + bias[o]
// Grid: x = i-tile (fastest; same-i blocks land on one XCD: dId stride 16 % 8 == 0)
// ---------------------------------------------------------------------------
__global__ __launch_bounds__(256) void k_gemm_out(
    const unsigned short* __restrict__ P,
    const unsigned short* __restrict__ hpT,
    const float* __restrict__ bf,
    void* __restrict__ outp, const unsigned short* __restrict__ h_raw)
{
    bool isf = detect_isf32(h_raw);
    int ib = blockIdx.z;
    int i0 = blockIdx.x * BM;
    int o0 = blockIdx.y * BN;
    const unsigned short* A  = P   + (size_t)ib * NN * NN;
    const unsigned short* Bt = hpT + (size_t)ib * FOUT * NN;

    __shared__ __align__(16) unsigned short As[BM * BK];
    __shared__ __align__(16) unsigned short Bs[BN * BK];

    int t = threadIdx.x;
    int lane = t & 63, wave = t >> 6;
    int wm = (wave & 1) * 64, wn = (wave >> 1) * 64;
    int lm = lane & 15, quad = lane >> 4;
    int rr = lane >> 3;
    int cc = lane & 7;
    int gc = cc ^ rr;
    int e  = lm & 7;

    float4v acc[4][4] = {};

    for (int k0 = 0; k0 < NN; k0 += BK) {
        __syncthreads();
        #pragma unroll
        for (int p = 0; p < 4; ++p) {
            int r0 = wave * 32 + p * 8;
            async_copy16(&As[r0 * BK], A  + (size_t)(i0 + r0 + rr) * NN + k0 + gc * 8);
            async_copy16(&Bs[r0 * BK], Bt + (size_t)(o0 + r0 + rr) * NN + k0 + gc * 8);
        }
        __syncthreads();
        #pragma unroll
        for (int kk = 0; kk < 2; ++kk) {
            int slot = ((kk << 2) | quad) ^ e;
            short8 fa[4], fb[4];
            #pragma unroll
            for (int mt = 0; mt < 4; ++mt)
                fa[mt] = *(const short8*)&As[(wm + mt * 16 + lm) * BK + slot * 8];
            #pragma unroll
            for (int nt = 0; nt < 4; ++nt)
                fb[nt] = *(const short8*)&Bs[(wn + nt * 16 + lm) * BK + slot * 8];
            #pragma unroll
            for (int mt = 0; mt < 4; ++mt)
                #pragma unroll
                for (int nt = 0; nt < 4; ++nt)
                    acc[mt][nt] = __builtin_amdgcn_mfma_f32_16x16x32_bf16(
                        fa[mt], fb[nt], acc[mt][nt], 0, 0, 0);
        }
    }

    if (isf) {
        float* C = (float*)outp + (size_t)ib * NN * FOUT;
        #pragma unroll
        for (int nt = 0; nt < 4; ++nt) {
            int o = o0 + wn + nt * 16 + lm;
            float bv = bf[o];
            #pragma unroll
            for (int mt = 0; mt < 4; ++mt) {
                int i = i0 + wm + mt * 16 + quad * 4;
                #pragma unroll
                for (int r = 0; r < 4; ++r)
                    C[(size_t)(i + r) * FOUT + o] = acc[mt][nt][r] + bv;
            }
        }
    } else {
        unsigned short* C = (unsigned short*)outp + (size_t)ib * NN * FOUT;
        #pragma unroll
        for (int nt = 0; nt < 4; ++nt) {
            int o = o0 + wn + nt * 16 + lm;
            float bv = bf[o];
            #pragma unroll
            for (int mt = 0; mt < 4; ++mt) {
                int i = i0 + wm + mt * 16 + quad * 4;
                #pragma unroll
                for (int r = 0; r < 4; ++r)
                    C[(size_t)(i + r) * FOUT + o] = f2bits(acc[mt][nt][r] + bv);
            }
        }
    }
}

// ---------------------------------------------------------------------------
extern "C" void kernel_launch(void* const* d_in, const int* in_sizes, int n_in,
                              void* d_out, int out_size, void* d_ws, size_t ws_size,
                              hipStream_t stream)
{
    const void* h_raw   = d_in[0];
    const void* adj_raw = d_in[1];
    const void* w_raw   = d_in[2];
    const void* as_raw  = d_in[3];
    const void* ad_raw  = d_in[4];
    const void* b_raw   = d_in[5];

    char* ws = (char*)d_ws;
    size_t off = 0;
    unsigned short* hpT = (unsigned short*)(ws + off); off += (size_t)BS * NH * FOUT * NN * 2;
    float* asr = (float*)(ws + off);            off += (size_t)BS * NH * NN * 4;
    float* ads = (float*)(ws + off);            off += (size_t)BS * NH * NN * 4;
    // union: {h_bf16, wt_bf16} live only until k_gemm_hw; P overlays after.
    size_t uoff = off;
    unsigned short* P    = (unsigned short*)(ws + uoff);
    unsigned short* h_bf = (unsigned short*)(ws + uoff); uoff += (size_t)BS * NN * FIN * 2;
    unsigned short* wt_b = (unsigned short*)(ws + uoff); uoff += (size_t)NH * FOUT * FIN * 2;
    off += (size_t)BS * NH * NN * NN * 2;       // P dominates the union
    float* asf = (float*)(ws + off);            off += (size_t)NH * FOUT * 4;
    float* adf = (float*)(ws + off);            off += (size_t)NH * FOUT * 4;
    float* bff = (float*)(ws + off);            off += 4096;

    k_prep<<<NB_H + NB_W + NB_Z + 1, 256, 0, stream>>>(
        h_raw, h_bf, w_raw, wt_b, as_raw, ad_raw, b_raw, asf, adf, bff, asr);
    k_gemm_hw<<<dim3(NN / BM, FOUT / BN, BS * NH), 256, 0, stream>>>(
        h_bf, wt_b, hpT, asf, adf, asr, ads);
    k_softmax_p<<<dim3(BS * NN), 256, 0, stream>>>(asr, ads, adj_raw, P);
    k_gemm_out<<<dim3(NN / BM, FOUT / BN, BS * NH), 256, 0, stream>>>(
        P, hpT, bff, d_out, (const unsigned short*)h_raw);
}